// Round 2
// baseline (232.263 us; speedup 1.0000x reference)
//
#include <hip/hip_runtime.h>

// SpikingCell recurrence, dead-code-eliminated:
//   clamp gate always true (clamp starts 0, only decrements; gate is <=0)
//   sc (spike counter) never returned
// Per-(b,n) recurrence over t:
//   dvi = (refrac >= 2) ? buf : 0
//   v += dvi; out = (v >= 1); v -= out
//   refrac = out ? 0 : refrac + 1
//   buf = x[b,t,n]
//
// R1 analysis: R0 (float2/thread, 256 blocks, unroll 8) was latency-bound:
// 4 waves/CU, VALUBusy 7.9%, 1.6 TB/s. Fix: scalar element per thread
// (512 blocks -> 2 blocks/CU, 8 waves/CU) + explicit double-buffered
// register pipeline (U=16) so 16 loads/thread are in flight while the
// previous group computes/stores.

constexpr int B = 16;
constexpr int T = 256;
constexpr int N = 8192;
constexpr int U = 16;  // pipeline group size (T % (2*U) == 0)

__global__ __launch_bounds__(256, 2) void spiking_kernel(
    const float* __restrict__ x, float* __restrict__ out) {
  const int c = blockIdx.x * blockDim.x + threadIdx.x;  // 0 .. B*N-1
  const int b = c >> 13;        // c / N
  const int n = c & (N - 1);    // c % N

  const float* __restrict__ xp = x + (size_t)b * T * N + n;
  float* __restrict__ op = out + (size_t)b * T * N + n;

  float v = 0.f, refrac = 0.f, buf = 0.f;

  float cur[U], nxt[U];

  // Prologue: load group 0.
#pragma unroll
  for (int u = 0; u < U; ++u) cur[u] = xp[(size_t)u * N];

  for (int g = 0; g < T / U - 1; ++g) {
    const size_t base_next = (size_t)(g + 1) * U * N;
    // Issue next group's loads first — independent of the state chain.
#pragma unroll
    for (int u = 0; u < U; ++u) nxt[u] = xp[base_next + (size_t)u * N];

    // Compute + store group g from registers (no load dependence).
    const size_t base_cur = (size_t)g * U * N;
#pragma unroll
    for (int u = 0; u < U; ++u) {
      const float dvi = (refrac >= 2.0f) ? buf : 0.0f;
      v += dvi;
      const float o = (v >= 1.0f) ? 1.0f : 0.0f;
      v -= o;
      refrac = (o == 0.0f) ? (refrac + 1.0f) : 0.0f;
      buf = cur[u];
      op[base_cur + (size_t)u * N] = o;
    }

#pragma unroll
    for (int u = 0; u < U; ++u) cur[u] = nxt[u];
  }

  // Epilogue: last group.
  const size_t base_last = (size_t)(T - U) * N;
#pragma unroll
  for (int u = 0; u < U; ++u) {
    const float dvi = (refrac >= 2.0f) ? buf : 0.0f;
    v += dvi;
    const float o = (v >= 1.0f) ? 1.0f : 0.0f;
    v -= o;
    refrac = (o == 0.0f) ? (refrac + 1.0f) : 0.0f;
    buf = cur[u];
    op[base_last + (size_t)u * N] = o;
  }
}

extern "C" void kernel_launch(void* const* d_in, const int* in_sizes, int n_in,
                              void* d_out, int out_size, void* d_ws,
                              size_t ws_size, hipStream_t stream) {
  const float* x = (const float*)d_in[0];
  float* out = (float*)d_out;

  const int threads = 256;
  const int total = B * N;             // one thread per element
  const int blocks = total / threads;  // 512 blocks -> 2 blocks/CU
  spiking_kernel<<<blocks, threads, 0, stream>>>(x, out);
}